// Round 5
// baseline (71.078 us; speedup 1.0000x reference)
//
#include <hip/hip_runtime.h>

// Reprojection residual for bundle adjustment.
// Inputs (setup_inputs order):
//   d_in[0] observe : float32 [N_OBS, 2]
//   d_in[1] cidx    : int32   [N_OBS]
//   d_in[2] pidx    : int32   [N_OBS]
//   d_in[3] K       : float32 [N_CAMS, 3]   (focal, k1, k2)
//   d_in[4] C       : float32 [N_CAMS, 7]   (t.xyz, q.xyzw)
//   d_in[5] P       : float32 [N_PTS, 3]
// Output: float32 [N_OBS, 2]
//
// R5: R4 was latency/issue-bound (70us, HBM 38%, VALU 12.6%, occ 33%).
//  1) P gather: one dwordx3 per obs instead of 3 scalar dwords (3x less
//     TA/L1 divergent-gather serialization).
//  2) Camera LDS packed to 10 floats/cam in 3 arrays (Q vf4 / T+f vf4 /
//     k1k2 vf2) = 80,000 B -> 2 blocks/CU (was 96KB -> 1 block/CU).
//     __launch_bounds__(1024,8) caps VGPR at 64 so both blocks fit:
//     32 waves/CU for latency hiding.
//  3) Persistent grid (512 blocks, grid-stride): LDS fill traffic
//     98MB -> 41MB and fill cost amortized.

typedef int   vi4 __attribute__((ext_vector_type(4)));
typedef float vf4 __attribute__((ext_vector_type(4)));
typedef float vf2 __attribute__((ext_vector_type(2)));
typedef float vf3 __attribute__((ext_vector_type(3), aligned(4)));

__device__ __forceinline__ void reproj_one(
    float vx, float vy, float vz,
    vf4 q, vf4 tf, vf2 d,
    float obx, float oby, float* ox, float* oy)
{
    float qx = q.x, qy = q.y, qz = q.z, qw = q.w;
    float tx = tf.x, ty = tf.y, tz = tf.z, f = tf.w;
    float k1 = d.x, k2 = d.y;

    // uv = cross(qv, v)
    float uvx = qy * vz - qz * vy;
    float uvy = qz * vx - qx * vz;
    float uvz = qx * vy - qy * vx;
    // uuv = cross(qv, uv)
    float uuvx = qy * uvz - qz * uvy;
    float uuvy = qz * uvx - qx * uvz;
    float uuvz = qx * uvy - qy * uvx;

    float cpx = vx + 2.0f * (qw * uvx + uuvx) + tx;
    float cpy = vy + 2.0f * (qw * uvy + uuvy) + ty;
    float cpz = vz + 2.0f * (qw * uvz + uuvz) + tz;

    float nx = -cpx / cpz;
    float ny = -cpy / cpz;
    float r  = nx * nx + ny * ny;

    float dist = 1.0f + k1 * r + k2 * r * r;
    float fd   = f * dist;

    *ox = fd * nx - obx;
    *oy = fd * ny - oby;
}

__global__ __launch_bounds__(1024, 8) void reproj_kernel(
    const float*  __restrict__ observe,
    const int*    __restrict__ cidx,
    const int*    __restrict__ pidx,
    const float*  __restrict__ K,
    const float*  __restrict__ C,
    const float*  __restrict__ P,
    float*        __restrict__ out,
    int n, int ncams)
{
    extern __shared__ float lds[];
    vf4* Qs = (vf4*)lds;                    // [ncams] qx,qy,qz,qw
    vf4* Ts = (vf4*)(lds + 4 * ncams);      // [ncams] tx,ty,tz,f
    vf2* Ds = (vf2*)(lds + 8 * ncams);      // [ncams] k1,k2

    // ---- cooperative LDS fill: all cameras resident (10 floats/cam) ----
    for (int c = threadIdx.x; c < ncams; c += 1024) {
        const float* Cc = C + 7 * c;
        const float* Kc = K + 3 * c;
        vf4 q  = { Cc[3], Cc[4], Cc[5], Cc[6] };
        vf4 tf = { Cc[0], Cc[1], Cc[2], Kc[0] };
        vf2 d  = { Kc[1], Kc[2] };
        Qs[c] = q; Ts[c] = tf; Ds[c] = d;
    }
    __syncthreads();

    int tid    = blockIdx.x * 1024 + threadIdx.x;
    int stride = gridDim.x * 1024 * 4;

    for (int base = tid * 4; base < n; base += stride) {
        if (base + 4 <= n) {
            // streaming loads (nontemporal, vectorized)
            vi4 c4 = __builtin_nontemporal_load((const vi4*)(cidx + base));
            vi4 p4 = __builtin_nontemporal_load((const vi4*)(pidx + base));
            vf4 ob01 = __builtin_nontemporal_load((const vf4*)(observe + 2 * base));
            vf4 ob23 = __builtin_nontemporal_load((const vf4*)(observe + 2 * base + 4));

            int ci[4] = { c4.x, c4.y, c4.z, c4.w };
            int pi[4] = { p4.x, p4.y, p4.z, p4.w };

            // issue all P gathers first: ONE dwordx3 per obs
            vf3 v0 = *(const vf3*)(P + 3 * pi[0]);
            vf3 v1 = *(const vf3*)(P + 3 * pi[1]);
            vf3 v2 = *(const vf3*)(P + 3 * pi[2]);
            vf3 v3 = *(const vf3*)(P + 3 * pi[3]);

            float res[8];
            reproj_one(v0.x, v0.y, v0.z, Qs[ci[0]], Ts[ci[0]], Ds[ci[0]],
                       ob01.x, ob01.y, &res[0], &res[1]);
            reproj_one(v1.x, v1.y, v1.z, Qs[ci[1]], Ts[ci[1]], Ds[ci[1]],
                       ob01.z, ob01.w, &res[2], &res[3]);
            reproj_one(v2.x, v2.y, v2.z, Qs[ci[2]], Ts[ci[2]], Ds[ci[2]],
                       ob23.x, ob23.y, &res[4], &res[5]);
            reproj_one(v3.x, v3.y, v3.z, Qs[ci[3]], Ts[ci[3]], Ds[ci[3]],
                       ob23.z, ob23.w, &res[6], &res[7]);

            vf4 o0 = { res[0], res[1], res[2], res[3] };
            vf4 o1 = { res[4], res[5], res[6], res[7] };
            __builtin_nontemporal_store(o0, (vf4*)(out + 2 * base));
            __builtin_nontemporal_store(o1, (vf4*)(out + 2 * base + 4));
        } else {
            for (int i = base; i < n; ++i) {
                int c = cidx[i];
                int p = pidx[i];
                vf3 pv = *(const vf3*)(P + 3 * p);
                float ox, oy;
                reproj_one(pv.x, pv.y, pv.z, Qs[c], Ts[c], Ds[c],
                           observe[2 * i], observe[2 * i + 1], &ox, &oy);
                out[2 * i]     = ox;
                out[2 * i + 1] = oy;
            }
        }
    }
}

extern "C" void kernel_launch(void* const* d_in, const int* in_sizes, int n_in,
                              void* d_out, int out_size, void* d_ws, size_t ws_size,
                              hipStream_t stream)
{
    const float* observe = (const float*)d_in[0];
    const int*   cidx    = (const int*)d_in[1];
    const int*   pidx    = (const int*)d_in[2];
    const float* K       = (const float*)d_in[3];
    const float* C       = (const float*)d_in[4];
    const float* P       = (const float*)d_in[5];
    float*       out     = (float*)d_out;

    int n     = in_sizes[1];          // N_OBS
    int ncams = in_sizes[3] / 3;      // K is [N_CAMS, 3]

    int block = 1024;
    // persistent grid: 2 blocks/CU on 256 CUs
    int grid = 512;
    int need = (n + block * 4 - 1) / (block * 4);
    if (grid > need) grid = need;
    size_t lds_bytes = (size_t)ncams * 10 * sizeof(float);   // 80,000 B

    reproj_kernel<<<grid, block, lds_bytes, stream>>>(
        observe, cidx, pidx, K, C, P, out, n, ncams);
}